// Round 12
// baseline (217.840 us; speedup 1.0000x reference)
//
#include <hip/hip_runtime.h>
#include <hip/hip_bf16.h>

// VectorQuantize: B=16, D=256, T=4096, K=1024.  FUSED pipeline (3 kernels):
//   prep    : W -> fp16 (x1024) chunk-linear MFMA layout, wsq, zero counts/lsum.
//   fused   : 256 blocks x 256 thr (4 waves), block owns 256 rows (one b).
//             64 rows/wave (4 m-tiles) -> per-CU w16 L1 traffic halved to 2 MB.
//             P0: 8 x 32-t quarters -> LDS transpose -> afrag[4][8] (fp16 regs).
//             P1: rank vs 1024 codes, barrier-free reg-stream double buffer,
//                 top-4/row -> cand in LDS.
//             P2: 8 quarters: x re-read (L2-hot) -> fp64 refine -> winner/counts/
//                 loss -> conflict-free w-gather (8 rows x 8 cols per wave) -> emit.
//   finalize: vq_loss + perplexity.

#define DD   256
#define KK   1024
#define TT   4096
#define BBB  16
#define NROW (BBB*TT)

typedef _Float16 half8 __attribute__((ext_vector_type(8)));
typedef float f32x4 __attribute__((ext_vector_type(4)));

__device__ __forceinline__ unsigned umaxu(unsigned a, unsigned b) { return a > b ? a : b; }
__device__ __forceinline__ unsigned uminu(unsigned a, unsigned b) { return a < b ? a : b; }

// ---------------- prep ----------------
// dst layout (halves): (((chunk*8+ks)*4+q)*16+n)*8 + j ; k = chunk*16+n, d = ks*32+q*8+j.
__global__ void prep(const float* __restrict__ w, _Float16* __restrict__ w16,
                     unsigned* __restrict__ counts, double* __restrict__ lsum,
                     float* __restrict__ wsq) {
    int gid = blockIdx.x * 256 + threadIdx.x;      // 0..32767
    int k = gid >> 5;                              // code 0..1023
    int c = gid & 31;                              // d-chunk of 8
    int chunk = k >> 4, n = k & 15;
    int ks = c >> 2, q = c & 3;
    const float* src = w + (k << 8) + (c << 3);
    union { uint4 u; _Float16 h[8]; } pk;
#pragma unroll
    for (int j = 0; j < 8; ++j) pk.h[j] = (_Float16)(src[j] * 1024.0f);
    size_t dst = ((((size_t)chunk * 8 + ks) * 4 + q) * 16 + n) * 8;
    *(uint4*)(w16 + dst) = pk.u;
    if (c == 0) {
        const float4* wr4 = (const float4*)(w + (k << 8));
        float s = 0.f;
#pragma unroll 8
        for (int ii = 0; ii < 64; ++ii) {
            float4 v = wr4[ii];
            s += v.x * v.x + v.y * v.y + v.z * v.z + v.w * v.w;
        }
        wsq[k] = 512.0f * s;
    }
    if (gid < KK) counts[gid] = 0u;
    if (gid == KK) *lsum = 0.0;
}

// ---------------- fused ----------------
#define XLS 257

// coalesced x 32-t quarter load -> LDS transposed [t][d]
#define XLOAD(toff) do {                                                       \
    int _dr = tid >> 3;                                                        \
    int _t4 = (tid & 7) << 2;                                                  \
    const float* _xb = x + ((size_t)b << 20) + t0 + (toff) + _t4;              \
    _Pragma("unroll")                                                          \
    for (int _pass = 0; _pass < 8; ++_pass) {                                  \
        int _d = (_pass << 5) + _dr;                                           \
        float4 _v = *(const float4*)(_xb + ((size_t)_d << 12));                \
        xt[(_t4 + 0) * XLS + _d] = _v.x;                                       \
        xt[(_t4 + 1) * XLS + _d] = _v.y;                                       \
        xt[(_t4 + 2) * XLS + _d] = _v.z;                                       \
        xt[(_t4 + 3) * XLS + _d] = _v.w;                                       \
    }                                                                          \
} while (0)

// load chunk `chn`'s 8 k-slices into named half8 regs PFX0..PFX7
#define LOADB(PFX, chn) do {                                                   \
    const uint4* _p = wsrc + ((chn) << 9) + lane;                              \
    PFX##0 = *(const half8*)(_p);                                              \
    PFX##1 = *(const half8*)(_p + 64);                                         \
    PFX##2 = *(const half8*)(_p + 128);                                        \
    PFX##3 = *(const half8*)(_p + 192);                                        \
    PFX##4 = *(const half8*)(_p + 256);                                        \
    PFX##5 = *(const half8*)(_p + 320);                                        \
    PFX##6 = *(const half8*)(_p + 384);                                        \
    PFX##7 = *(const half8*)(_p + 448);                                        \
} while (0)

#define MFMA16(A, B, C) __builtin_amdgcn_mfma_f32_16x16x32_f16((A), (B), (C), 0, 0, 0)

// one k-slice: 4 m-tiles against shared B fragment
#define MStep(KS, PFX)                                                         \
    a0 = MFMA16(afrag[0][KS], PFX##KS, a0);                                    \
    a1 = MFMA16(afrag[1][KS], PFX##KS, a1);                                    \
    a2 = MFMA16(afrag[2][KS], PFX##KS, a2);                                    \
    a3 = MFMA16(afrag[3][KS], PFX##KS, a3);

// compute chunk `ch` (4 m-tiles) against PFX0..PFX7, update b1/b2[16]
#define COMPUTE4(ch, PFX) do {                                                 \
    f32x4 a0 = {0.f, 0.f, 0.f, 0.f};                                           \
    f32x4 a1 = {0.f, 0.f, 0.f, 0.f};                                           \
    f32x4 a2 = {0.f, 0.f, 0.f, 0.f};                                           \
    f32x4 a3 = {0.f, 0.f, 0.f, 0.f};                                           \
    MStep(0, PFX) MStep(1, PFX) MStep(2, PFX) MStep(3, PFX)                    \
    MStep(4, PFX) MStep(5, PFX) MStep(6, PFX) MStep(7, PFX)                    \
    unsigned kg = (unsigned)(((ch) << 4) + n);                                 \
    float csub = wsql[kg];                                                     \
    _Pragma("unroll")                                                          \
    for (int i = 0; i < 4; ++i) {                                              \
        float v; unsigned p, o;                                                \
        v = fmaxf(a0[i] - csub, 0.0f);                                         \
        p = (__float_as_uint(v) & 0xFFFFFC00u) | kg;                           \
        o = b1[i];                                                             \
        b2[i] = umaxu(b2[i], uminu(p, o));                                     \
        b1[i] = umaxu(o, p);                                                   \
        v = fmaxf(a1[i] - csub, 0.0f);                                         \
        p = (__float_as_uint(v) & 0xFFFFFC00u) | kg;                           \
        o = b1[4 + i];                                                         \
        b2[4 + i] = umaxu(b2[4 + i], uminu(p, o));                             \
        b1[4 + i] = umaxu(o, p);                                               \
        v = fmaxf(a2[i] - csub, 0.0f);                                         \
        p = (__float_as_uint(v) & 0xFFFFFC00u) | kg;                           \
        o = b1[8 + i];                                                         \
        b2[8 + i] = umaxu(b2[8 + i], uminu(p, o));                             \
        b1[8 + i] = umaxu(o, p);                                               \
        v = fmaxf(a3[i] - csub, 0.0f);                                         \
        p = (__float_as_uint(v) & 0xFFFFFC00u) | kg;                           \
        o = b1[12 + i];                                                        \
        b2[12 + i] = umaxu(b2[12 + i], uminu(p, o));                           \
        b1[12 + i] = umaxu(o, p);                                              \
    }                                                                          \
} while (0)

__global__ __launch_bounds__(256, 1) void fused(const float* __restrict__ x,
                                                const float* __restrict__ w,
                                                const _Float16* __restrict__ w16,
                                                const float* __restrict__ wsq,
                                                float* __restrict__ out,
                                                unsigned* __restrict__ counts,
                                                double* __restrict__ lsum) {
    __shared__ __align__(16) float xt[32 * XLS];   // 32.9 KB; x quarter / w-gather
    __shared__ __align__(16) float wsql[KK];       // 4 KB
    __shared__ __align__(16) uint4 cndl[256];      // 4 KB: top-4 per row
    __shared__ double disl[32][4];
    __shared__ int winner[32];
    __shared__ double ldis[32];

    int tid = threadIdx.x, bid = blockIdx.x;
    int b = bid >> 4;
    int t0 = (bid & 15) << 8;                      // 256 rows per block
    int lane = tid & 63, wv = tid >> 6;
    int n = lane & 15, q = lane >> 4;

    ((float4*)wsql)[tid] = ((const float4*)wsq)[tid];

    // ---- P0: 8 quarter-loads; wave wv extracts quarters 2wv / 2wv+1 ----
    // wave rows: wv*64 + mt*16 + n (mt 0..3); quarter of row = 2wv + (mt>>1).
    half8 afrag[4][8];
#pragma unroll
    for (int q8 = 0; q8 < 8; ++q8) {
        XLOAD(q8 << 5);
        __syncthreads();
        if ((q8 >> 1) == wv) {
            const int mt_hi = q8 & 1;
#pragma unroll
            for (int ml = 0; ml < 2; ++ml) {
                const int mt = (mt_hi << 1) + ml;
                int rl = (ml << 4) + n;            // row within this quarter
#pragma unroll
                for (int ks = 0; ks < 8; ++ks) {
                    const float* sp = &xt[rl * XLS + (ks << 5) + (q << 3)];
                    half8 f;
#pragma unroll
                    for (int j = 0; j < 8; ++j) f[j] = (_Float16)sp[j];
                    afrag[mt][ks] = f;
                }
            }
        }
        __syncthreads();
    }

    // ---- P1: rank (barrier-free reg-stream, 4 m-tiles/chunk) ----
    unsigned b1[16], b2[16];
#pragma unroll
    for (int i = 0; i < 16; ++i) { b1[i] = 0u; b2[i] = 0u; }

    const uint4* wsrc = (const uint4*)w16;
    half8 bA0, bA1, bA2, bA3, bA4, bA5, bA6, bA7;
    half8 bB0, bB1, bB2, bB3, bB4, bB5, bB6, bB7;

    LOADB(bA, 0);
    for (int ch = 0; ch < 64; ch += 2) {
        LOADB(bB, ch + 1);
        COMPUTE4(ch, bA);
        if (ch + 2 < 64) LOADB(bA, ch + 2);
        COMPUTE4(ch + 1, bB);
    }

    // merge the 16 column-lanes' top-2 -> per-row top-4 -> cndl (LDS)
    // s = tile*4 + reg; row_local = wv*64 + tile*16 + q*4 + reg
#pragma unroll
    for (int s = 0; s < 16; ++s) {
        unsigned v0 = b1[s], v1 = b2[s], v2 = 0u, v3 = 0u;
#pragma unroll
        for (int m = 1; m <= 8; m <<= 1) {
            unsigned e0 = __shfl_xor(v0, m);
            unsigned e1 = __shfl_xor(v1, m);
            unsigned e2 = __shfl_xor(v2, m);
            unsigned e3 = __shfl_xor(v3, m);
#pragma unroll
            for (int u = 0; u < 4; ++u) {
                unsigned e = (u == 0) ? e0 : (u == 1) ? e1 : (u == 2) ? e2 : e3;
                unsigned t;
                t = umaxu(e, v0); e = uminu(e, v0); v0 = t;
                t = umaxu(e, v1); e = uminu(e, v1); v1 = t;
                t = umaxu(e, v2); e = uminu(e, v2); v2 = t;
                v3 = umaxu(e, v3);
            }
        }
        if (n == 0) {
            int row_local = (wv << 6) + ((s >> 2) << 4) + (q << 2) + (s & 3);
            cndl[row_local] = make_uint4(v0, v1, v2, v3);
        }
    }
    __syncthreads();

    // ---- P2: 8 quarters of {x reload, fp64 refine, winner, gather, emit, loss} ----
    int c = lane >> 4, dl = lane & 15;
    int rr2 = lane >> 3, c8 = lane & 7;            // gather lane mapping
    for (int qt = 0; qt < 8; ++qt) {
        XLOAD(qt << 5);                            // L2-hot re-read
        __syncthreads();

        // refine: 4 waves x 8 rows, 4 candidates x 16 d-lanes per row
#pragma unroll
        for (int rr = 0; rr < 8; ++rr) {
            int r = (wv << 3) + rr;
            unsigned ci = ((const unsigned*)cndl)[(((qt << 5) + r) << 2) + c] & 1023u;
            const float* wr = w + (ci << 8);
            double s = 0.0;
#pragma unroll
            for (int dd = 0; dd < 4; ++dd) {
                int d4 = (dd << 6) + (dl << 2);
                float4 xv = *(const float4*)(&xt[r * XLS + d4]);
                float4 wv4 = *(const float4*)(wr + d4);
                double e;
                e = (double)xv.x - (double)wv4.x; s = fma(e, e, s);
                e = (double)xv.y - (double)wv4.y; s = fma(e, e, s);
                e = (double)xv.z - (double)wv4.z; s = fma(e, e, s);
                e = (double)xv.w - (double)wv4.w; s = fma(e, e, s);
            }
#pragma unroll
            for (int m = 1; m <= 8; m <<= 1) s += __shfl_xor(s, m);
            if (dl == 0) disl[r][c] = s;
        }
        __syncthreads();

        // winner selection (tie -> smaller index), counts, per-row loss
        if (tid < 32) {
            uint4 cc = cndl[(qt << 5) + tid];
            unsigned i0 = cc.x & 1023u, i1 = cc.y & 1023u, i2 = cc.z & 1023u, i3 = cc.w & 1023u;
            double dm = disl[tid][0]; unsigned ci = i0;
            double dk;
            dk = disl[tid][1]; if (dk < dm || (dk == dm && i1 < ci)) { dm = dk; ci = i1; }
            dk = disl[tid][2]; if (dk < dm || (dk == dm && i2 < ci)) { dm = dk; ci = i2; }
            dk = disl[tid][3]; if (dk < dm || (dk == dm && i3 < ci)) { dm = dk; ci = i3; }
            winner[tid] = (int)ci;
            ldis[tid] = dm;
            atomicAdd(&counts[ci], 1u);
        }
        __syncthreads();

        // gather winner w rows into LDS (reuse xt): wave wv owns rows wv*8..wv*8+7,
        // lane (rr2, c8) covers 64B column slices -> 2-way LDS banks (free)
        {
            int rowr = (wv << 3) + rr2;
            int win = winner[rowr];
            const float* wrow = w + (win << 8);
#pragma unroll
            for (int cc2 = 0; cc2 < 4; ++cc2) {
                int col = (cc2 << 6) + (c8 << 3);
                float4 g0 = *(const float4*)(wrow + col);
                float4 g1 = *(const float4*)(wrow + col + 4);
                *(float4*)(&xt[rowr * XLS + col]) = g0;
                *(float4*)(&xt[rowr * XLS + col + 4]) = g1;
            }
        }
        __syncthreads();

        // emit: out[b][d][t0+qt*32+t] = xt[t][d], coalesced float4 along t
        {
            int dr = tid >> 3;
            int t4 = (tid & 7) << 2;
            float* ob = out + ((size_t)b << 20) + t0 + (qt << 5) + t4;
#pragma unroll
            for (int pass = 0; pass < 8; ++pass) {
                int d = (pass << 5) + dr;
                float4 o;
                o.x = xt[(t4 + 0) * XLS + d];
                o.y = xt[(t4 + 1) * XLS + d];
                o.z = xt[(t4 + 2) * XLS + d];
                o.w = xt[(t4 + 3) * XLS + d];
                *(float4*)(ob + ((size_t)d << 12)) = o;
            }
        }

        // loss reduction
        __syncthreads();
        if (tid < 16) ldis[tid] += ldis[tid + 16];
        __syncthreads();
        if (tid < 8) ldis[tid] += ldis[tid + 8];
        __syncthreads();
        if (tid < 4) ldis[tid] += ldis[tid + 4];
        __syncthreads();
        if (tid < 2) ldis[tid] += ldis[tid + 2];
        __syncthreads();
        if (tid == 0) atomicAdd(lsum, ldis[0] + ldis[1]);
        __syncthreads();                            // protect xt/ldis for next quarter
    }
}

// ---------------- finalize ----------------
__global__ void finalize(const unsigned* __restrict__ counts,
                         const double* __restrict__ lsum,
                         float* __restrict__ out2) {
    __shared__ double part[256];
    int tid = threadIdx.x;
    double s = 0.0;
    for (int i = tid; i < KK; i += 256) {
        double p = (double)counts[i] / (double)NROW;
        s += p * log(p + 1e-10);
    }
    part[tid] = s;
    __syncthreads();
    for (int st = 128; st > 0; st >>= 1) {
        if (tid < st) part[tid] += part[tid + st];
        __syncthreads();
    }
    if (tid == 0) {
        out2[0] = (float)(1.25 * (*lsum) / ((double)NROW * (double)DD));
        out2[1] = (float)exp(-part[0]);
    }
}

extern "C" void kernel_launch(void* const* d_in, const int* in_sizes, int n_in,
                              void* d_out, int out_size, void* d_ws, size_t ws_size,
                              hipStream_t stream) {
    const float* x = (const float*)d_in[0];
    const float* w = (const float*)d_in[1];
    float* out = (float*)d_out;
    char* ws = (char*)d_ws;
    _Float16* w16    = (_Float16*)ws;                         // 524288 B
    unsigned* counts = (unsigned*)(ws + 524288);              // 4 KB
    float*    wsq    = (float*)(ws + 528384);                 // 4 KB
    double*   lsum   = (double*)(ws + 532480);                // 8 B

    prep<<<128, 256, 0, stream>>>(w, w16, counts, lsum, wsq);
    fused<<<256, 256, 0, stream>>>(x, w, w16, wsq, out, counts, lsum);
    finalize<<<1, 256, 0, stream>>>(counts, lsum, out + (size_t)NROW * DD);
}

// Round 13
// 182.125 us; speedup vs baseline: 1.1961x; 1.1961x over previous
//
#include <hip/hip_runtime.h>
#include <hip/hip_bf16.h>

// VectorQuantize: B=16, D=256, T=4096, K=1024.  FUSED pipeline (3 kernels):
//   prep    : W -> fp16 (x1024) chunk-linear MFMA layout, wsq, zero counts/lsum.
//   fused   : 512 blocks x 256 thr (4 waves), block owns 128 rows (one b).
//             32 rows/wave (VGPR 88, NO spill — 64 rows/wave spills, measured 2x).
//             P0: 4 x 32-t quarters -> LDS transpose -> afrag[2][8] (fp16 regs).
//             P1: rank vs 1024 codes, barrier-free reg-stream double buffer,
//                 top-4/row -> cand in LDS.
//             P2: 4 quarters: x re-read (L2-hot) -> fp64 refine -> winner/counts/
//                 loss -> conflict-free w-gather (8 rows x 8 col-slices/wave) -> emit.
//   finalize: vq_loss + perplexity.

#define DD   256
#define KK   1024
#define TT   4096
#define BBB  16
#define NROW (BBB*TT)

typedef _Float16 half8 __attribute__((ext_vector_type(8)));
typedef float f32x4 __attribute__((ext_vector_type(4)));

__device__ __forceinline__ unsigned umaxu(unsigned a, unsigned b) { return a > b ? a : b; }
__device__ __forceinline__ unsigned uminu(unsigned a, unsigned b) { return a < b ? a : b; }

// ---------------- prep ----------------
// dst layout (halves): (((chunk*8+ks)*4+q)*16+n)*8 + j ; k = chunk*16+n, d = ks*32+q*8+j.
__global__ void prep(const float* __restrict__ w, _Float16* __restrict__ w16,
                     unsigned* __restrict__ counts, double* __restrict__ lsum,
                     float* __restrict__ wsq) {
    int gid = blockIdx.x * 256 + threadIdx.x;      // 0..32767
    int k = gid >> 5;                              // code 0..1023
    int c = gid & 31;                              // d-chunk of 8
    int chunk = k >> 4, n = k & 15;
    int ks = c >> 2, q = c & 3;
    const float* src = w + (k << 8) + (c << 3);
    union { uint4 u; _Float16 h[8]; } pk;
#pragma unroll
    for (int j = 0; j < 8; ++j) pk.h[j] = (_Float16)(src[j] * 1024.0f);
    size_t dst = ((((size_t)chunk * 8 + ks) * 4 + q) * 16 + n) * 8;
    *(uint4*)(w16 + dst) = pk.u;
    if (c == 0) {
        const float4* wr4 = (const float4*)(w + (k << 8));
        float s = 0.f;
#pragma unroll 8
        for (int ii = 0; ii < 64; ++ii) {
            float4 v = wr4[ii];
            s += v.x * v.x + v.y * v.y + v.z * v.z + v.w * v.w;
        }
        wsq[k] = 512.0f * s;
    }
    if (gid < KK) counts[gid] = 0u;
    if (gid == KK) *lsum = 0.0;
}

// ---------------- fused ----------------
#define XLS 257

// coalesced x 32-t quarter load -> LDS transposed [t][d]
#define XLOAD(toff) do {                                                       \
    int _dr = tid >> 3;                                                        \
    int _t4 = (tid & 7) << 2;                                                  \
    const float* _xb = x + ((size_t)b << 20) + t0 + (toff) + _t4;              \
    _Pragma("unroll")                                                          \
    for (int _pass = 0; _pass < 8; ++_pass) {                                  \
        int _d = (_pass << 5) + _dr;                                           \
        float4 _v = *(const float4*)(_xb + ((size_t)_d << 12));                \
        xt[(_t4 + 0) * XLS + _d] = _v.x;                                       \
        xt[(_t4 + 1) * XLS + _d] = _v.y;                                       \
        xt[(_t4 + 2) * XLS + _d] = _v.z;                                       \
        xt[(_t4 + 3) * XLS + _d] = _v.w;                                       \
    }                                                                          \
} while (0)

// load chunk `chn`'s 8 k-slices into named half8 regs PFX0..PFX7
#define LOADB(PFX, chn) do {                                                   \
    const uint4* _p = wsrc + ((chn) << 9) + lane;                              \
    PFX##0 = *(const half8*)(_p);                                              \
    PFX##1 = *(const half8*)(_p + 64);                                         \
    PFX##2 = *(const half8*)(_p + 128);                                        \
    PFX##3 = *(const half8*)(_p + 192);                                        \
    PFX##4 = *(const half8*)(_p + 256);                                        \
    PFX##5 = *(const half8*)(_p + 320);                                        \
    PFX##6 = *(const half8*)(_p + 384);                                        \
    PFX##7 = *(const half8*)(_p + 448);                                        \
} while (0)

#define MFMA16(A, B, C) __builtin_amdgcn_mfma_f32_16x16x32_f16((A), (B), (C), 0, 0, 0)

// compute chunk `ch` against named regs PFX0..PFX7, update b1/b2
#define COMPUTE(ch, PFX) do {                                                  \
    f32x4 a0 = {0.f, 0.f, 0.f, 0.f};                                           \
    f32x4 a1 = {0.f, 0.f, 0.f, 0.f};                                           \
    a0 = MFMA16(afrag[0][0], PFX##0, a0); a1 = MFMA16(afrag[1][0], PFX##0, a1);\
    a0 = MFMA16(afrag[0][1], PFX##1, a0); a1 = MFMA16(afrag[1][1], PFX##1, a1);\
    a0 = MFMA16(afrag[0][2], PFX##2, a0); a1 = MFMA16(afrag[1][2], PFX##2, a1);\
    a0 = MFMA16(afrag[0][3], PFX##3, a0); a1 = MFMA16(afrag[1][3], PFX##3, a1);\
    a0 = MFMA16(afrag[0][4], PFX##4, a0); a1 = MFMA16(afrag[1][4], PFX##4, a1);\
    a0 = MFMA16(afrag[0][5], PFX##5, a0); a1 = MFMA16(afrag[1][5], PFX##5, a1);\
    a0 = MFMA16(afrag[0][6], PFX##6, a0); a1 = MFMA16(afrag[1][6], PFX##6, a1);\
    a0 = MFMA16(afrag[0][7], PFX##7, a0); a1 = MFMA16(afrag[1][7], PFX##7, a1);\
    unsigned kg = (unsigned)(((ch) << 4) + n);                                 \
    float csub = wsql[kg];                                                     \
    _Pragma("unroll")                                                          \
    for (int i = 0; i < 4; ++i) {                                              \
        float v; unsigned p, o;                                                \
        v = fmaxf(a0[i] - csub, 0.0f);                                         \
        p = (__float_as_uint(v) & 0xFFFFFC00u) | kg;                           \
        o = b1[i];                                                             \
        b2[i] = umaxu(b2[i], uminu(p, o));                                     \
        b1[i] = umaxu(o, p);                                                   \
        v = fmaxf(a1[i] - csub, 0.0f);                                         \
        p = (__float_as_uint(v) & 0xFFFFFC00u) | kg;                           \
        o = b1[4 + i];                                                         \
        b2[4 + i] = umaxu(b2[4 + i], uminu(p, o));                             \
        b1[4 + i] = umaxu(o, p);                                               \
    }                                                                          \
} while (0)

__global__ __launch_bounds__(256, 2) void fused(const float* __restrict__ x,
                                                const float* __restrict__ w,
                                                const _Float16* __restrict__ w16,
                                                const float* __restrict__ wsq,
                                                float* __restrict__ out,
                                                unsigned* __restrict__ counts,
                                                double* __restrict__ lsum) {
    __shared__ __align__(16) float xt[32 * XLS];   // 32.9 KB; x quarter / w-gather
    __shared__ __align__(16) float wsql[KK];       // 4 KB
    __shared__ __align__(16) uint4 cndl[128];      // 2 KB: top-4 per row
    __shared__ double disl[32][4];
    __shared__ int winner[32];
    __shared__ double ldis[32];

    int tid = threadIdx.x, bid = blockIdx.x;
    int b = bid >> 5;
    int t0 = (bid & 31) << 7;                      // 128 rows per block
    int lane = tid & 63, wv = tid >> 6;
    int n = lane & 15, q = lane >> 4;

    ((float4*)wsql)[tid] = ((const float4*)wsq)[tid];

    // ---- P0: 4 quarter-loads; wave p extracts its afrag from quarter p ----
    half8 afrag[2][8];
#pragma unroll
    for (int p = 0; p < 4; ++p) {
        XLOAD(p << 5);
        __syncthreads();
        if (wv == p) {
#pragma unroll
            for (int mt = 0; mt < 2; ++mt) {
                int rl = (mt << 4) + n;            // t-local row within quarter
#pragma unroll
                for (int ks = 0; ks < 8; ++ks) {
                    const float* sp = &xt[rl * XLS + (ks << 5) + (q << 3)];
                    half8 f;
#pragma unroll
                    for (int j = 0; j < 8; ++j) f[j] = (_Float16)sp[j];
                    afrag[mt][ks] = f;
                }
            }
        }
        __syncthreads();
    }

    // ---- P1: rank (barrier-free reg-stream) ----
    unsigned b1[8], b2[8];
#pragma unroll
    for (int i = 0; i < 8; ++i) { b1[i] = 0u; b2[i] = 0u; }

    const uint4* wsrc = (const uint4*)w16;
    half8 bA0, bA1, bA2, bA3, bA4, bA5, bA6, bA7;
    half8 bB0, bB1, bB2, bB3, bB4, bB5, bB6, bB7;

    LOADB(bA, 0);
    for (int ch = 0; ch < 64; ch += 2) {
        LOADB(bB, ch + 1);
        COMPUTE(ch, bA);
        if (ch + 2 < 64) LOADB(bA, ch + 2);
        COMPUTE(ch + 1, bB);
    }

    // merge the 16 column-lanes' top-2 -> per-row top-4 -> cndl (LDS)
#pragma unroll
    for (int s = 0; s < 8; ++s) {
        unsigned v0 = b1[s], v1 = b2[s], v2 = 0u, v3 = 0u;
#pragma unroll
        for (int m = 1; m <= 8; m <<= 1) {
            unsigned e0 = __shfl_xor(v0, m);
            unsigned e1 = __shfl_xor(v1, m);
            unsigned e2 = __shfl_xor(v2, m);
            unsigned e3 = __shfl_xor(v3, m);
#pragma unroll
            for (int u = 0; u < 4; ++u) {
                unsigned e = (u == 0) ? e0 : (u == 1) ? e1 : (u == 2) ? e2 : e3;
                unsigned t;
                t = umaxu(e, v0); e = uminu(e, v0); v0 = t;
                t = umaxu(e, v1); e = uminu(e, v1); v1 = t;
                t = umaxu(e, v2); e = uminu(e, v2); v2 = t;
                v3 = umaxu(e, v3);
            }
        }
        if (n == 0) {
            int row_local = (wv << 5) + ((s >> 2) << 4) + (q << 2) + (s & 3);
            cndl[row_local] = make_uint4(v0, v1, v2, v3);
        }
    }
    __syncthreads();

    // ---- P2: 4 quarters of {x reload, fp64 refine, winner, gather, emit, loss} ----
    int c = lane >> 4, dl = lane & 15;
    int rr2 = lane >> 3, c8 = lane & 7;            // conflict-free gather mapping
    for (int qt = 0; qt < 4; ++qt) {
        XLOAD(qt << 5);                            // L2-hot re-read
        __syncthreads();

        // refine (cand from LDS)
#pragma unroll
        for (int rr = 0; rr < 8; ++rr) {
            int r = (wv << 3) + rr;
            unsigned ci = ((const unsigned*)cndl)[(((qt << 5) + r) << 2) + c] & 1023u;
            const float* wr = w + (ci << 8);
            double s = 0.0;
#pragma unroll
            for (int dd = 0; dd < 4; ++dd) {
                int d4 = (dd << 6) + (dl << 2);
                float4 xv = *(const float4*)(&xt[r * XLS + d4]);
                float4 wv4 = *(const float4*)(wr + d4);
                double e;
                e = (double)xv.x - (double)wv4.x; s = fma(e, e, s);
                e = (double)xv.y - (double)wv4.y; s = fma(e, e, s);
                e = (double)xv.z - (double)wv4.z; s = fma(e, e, s);
                e = (double)xv.w - (double)wv4.w; s = fma(e, e, s);
            }
#pragma unroll
            for (int m = 1; m <= 8; m <<= 1) s += __shfl_xor(s, m);
            if (dl == 0) disl[r][c] = s;
        }
        __syncthreads();

        // winner selection (tie -> smaller index), counts, per-row loss
        if (tid < 32) {
            uint4 cc = cndl[(qt << 5) + tid];
            unsigned i0 = cc.x & 1023u, i1 = cc.y & 1023u, i2 = cc.z & 1023u, i3 = cc.w & 1023u;
            double dm = disl[tid][0]; unsigned ci = i0;
            double dk;
            dk = disl[tid][1]; if (dk < dm || (dk == dm && i1 < ci)) { dm = dk; ci = i1; }
            dk = disl[tid][2]; if (dk < dm || (dk == dm && i2 < ci)) { dm = dk; ci = i2; }
            dk = disl[tid][3]; if (dk < dm || (dk == dm && i3 < ci)) { dm = dk; ci = i3; }
            winner[tid] = (int)ci;
            ldis[tid] = dm;
            atomicAdd(&counts[ci], 1u);
        }
        __syncthreads();

        // gather winner w rows into LDS (reuse xt): wave wv owns rows wv*8..wv*8+7,
        // lane (rr2, c8) -> 8 rows x 8 col-slices; banks (row + col) mod 32 ~2-way
        {
            int rowr = (wv << 3) + rr2;
            int win = winner[rowr];
            const float* wrow = w + (win << 8);
#pragma unroll
            for (int cc2 = 0; cc2 < 4; ++cc2) {
                int col = (cc2 << 6) + (c8 << 3);
                float4 g0 = *(const float4*)(wrow + col);
                float4 g1 = *(const float4*)(wrow + col + 4);
                *(float4*)(&xt[rowr * XLS + col]) = g0;
                *(float4*)(&xt[rowr * XLS + col + 4]) = g1;
            }
        }
        __syncthreads();

        // emit: out[b][d][t0+qt*32+t] = xt[t][d], coalesced float4 along t
        {
            int dr = tid >> 3;
            int t4 = (tid & 7) << 2;
            float* ob = out + ((size_t)b << 20) + t0 + (qt << 5) + t4;
#pragma unroll
            for (int pass = 0; pass < 8; ++pass) {
                int d = (pass << 5) + dr;
                float4 o;
                o.x = xt[(t4 + 0) * XLS + d];
                o.y = xt[(t4 + 1) * XLS + d];
                o.z = xt[(t4 + 2) * XLS + d];
                o.w = xt[(t4 + 3) * XLS + d];
                *(float4*)(ob + ((size_t)d << 12)) = o;
            }
        }

        // loss reduction
        __syncthreads();
        if (tid < 16) ldis[tid] += ldis[tid + 16];
        __syncthreads();
        if (tid < 8) ldis[tid] += ldis[tid + 8];
        __syncthreads();
        if (tid < 4) ldis[tid] += ldis[tid + 4];
        __syncthreads();
        if (tid < 2) ldis[tid] += ldis[tid + 2];
        __syncthreads();
        if (tid == 0) atomicAdd(lsum, ldis[0] + ldis[1]);
        __syncthreads();                            // protect xt/ldis for next quarter
    }
}

// ---------------- finalize ----------------
__global__ void finalize(const unsigned* __restrict__ counts,
                         const double* __restrict__ lsum,
                         float* __restrict__ out2) {
    __shared__ double part[256];
    int tid = threadIdx.x;
    double s = 0.0;
    for (int i = tid; i < KK; i += 256) {
        double p = (double)counts[i] / (double)NROW;
        s += p * log(p + 1e-10);
    }
    part[tid] = s;
    __syncthreads();
    for (int st = 128; st > 0; st >>= 1) {
        if (tid < st) part[tid] += part[tid + st];
        __syncthreads();
    }
    if (tid == 0) {
        out2[0] = (float)(1.25 * (*lsum) / ((double)NROW * (double)DD));
        out2[1] = (float)exp(-part[0]);
    }
}

extern "C" void kernel_launch(void* const* d_in, const int* in_sizes, int n_in,
                              void* d_out, int out_size, void* d_ws, size_t ws_size,
                              hipStream_t stream) {
    const float* x = (const float*)d_in[0];
    const float* w = (const float*)d_in[1];
    float* out = (float*)d_out;
    char* ws = (char*)d_ws;
    _Float16* w16    = (_Float16*)ws;                         // 524288 B
    unsigned* counts = (unsigned*)(ws + 524288);              // 4 KB
    float*    wsq    = (float*)(ws + 528384);                 // 4 KB
    double*   lsum   = (double*)(ws + 532480);                // 8 B

    prep<<<128, 256, 0, stream>>>(w, w16, counts, lsum, wsq);
    fused<<<512, 256, 0, stream>>>(x, w, w16, wsq, out, counts, lsum);
    finalize<<<1, 256, 0, stream>>>(counts, lsum, out + (size_t)NROW * DD);
}

// Round 14
// 181.487 us; speedup vs baseline: 1.2003x; 1.0035x over previous
//
#include <hip/hip_runtime.h>
#include <hip/hip_bf16.h>

// VectorQuantize: B=16, D=256, T=4096, K=1024.  FUSED pipeline (3 kernels):
//   prep    : W -> fp16 (x1024) chunk-linear MFMA layout, wsq, zero counts/lsum.
//   fused   : 512 blocks x 256 thr (4 waves), block owns 128 rows (one b).
//             32 rows/wave (VGPR 88 base, no spill; 64 r/w spills — measured 2x).
//             P0: 4 x 32-t quarters -> LDS transpose (xta) -> afrag[2][8].
//             P1: rank vs 1024 codes, barrier-free reg-stream double buffer,
//                 top-4/row -> cand in LDS. Quarter-0 x prefetched into regs
//                 BEFORE P1; ds_written to xta during post-merge barrier window.
//             P2: 4 quarters, double-buffered xta/xtb (T14 async-stage): x for
//                 qt+1 global->regs at top of qt body, ds_write at end. All P2
//                 barriers are lgkmcnt(0)+s_barrier (emit stores drain async).
//                 Loss via wave-0 shuffle reduce (no LDS tree).
//   finalize: vq_loss + perplexity.

#define DD   256
#define KK   1024
#define TT   4096
#define BBB  16
#define NROW (BBB*TT)

typedef _Float16 half8 __attribute__((ext_vector_type(8)));
typedef float f32x4 __attribute__((ext_vector_type(4)));

__device__ __forceinline__ unsigned umaxu(unsigned a, unsigned b) { return a > b ? a : b; }
__device__ __forceinline__ unsigned uminu(unsigned a, unsigned b) { return a < b ? a : b; }

// LDS-only barrier: emit's global stores keep draining in the background.
__device__ __forceinline__ void barrier_lgkm() {
    asm volatile("s_waitcnt lgkmcnt(0)" ::: "memory");
    __builtin_amdgcn_s_barrier();
    __builtin_amdgcn_sched_barrier(0);   // rule #18: pin ops behind the wait
}

// ---------------- prep ----------------
// dst layout (halves): (((chunk*8+ks)*4+q)*16+n)*8 + j ; k = chunk*16+n, d = ks*32+q*8+j.
__global__ void prep(const float* __restrict__ w, _Float16* __restrict__ w16,
                     unsigned* __restrict__ counts, double* __restrict__ lsum,
                     float* __restrict__ wsq) {
    int gid = blockIdx.x * 256 + threadIdx.x;      // 0..32767
    int k = gid >> 5;                              // code 0..1023
    int c = gid & 31;                              // d-chunk of 8
    int chunk = k >> 4, n = k & 15;
    int ks = c >> 2, q = c & 3;
    const float* src = w + (k << 8) + (c << 3);
    union { uint4 u; _Float16 h[8]; } pk;
#pragma unroll
    for (int j = 0; j < 8; ++j) pk.h[j] = (_Float16)(src[j] * 1024.0f);
    size_t dst = ((((size_t)chunk * 8 + ks) * 4 + q) * 16 + n) * 8;
    *(uint4*)(w16 + dst) = pk.u;
    if (c == 0) {
        const float4* wr4 = (const float4*)(w + (k << 8));
        float s = 0.f;
#pragma unroll 8
        for (int ii = 0; ii < 64; ++ii) {
            float4 v = wr4[ii];
            s += v.x * v.x + v.y * v.y + v.z * v.z + v.w * v.w;
        }
        wsq[k] = 512.0f * s;
    }
    if (gid < KK) counts[gid] = 0u;
    if (gid == KK) *lsum = 0.0;
}

// ---------------- fused ----------------
#define XLS 257

// coalesced x 32-t quarter load -> LDS transposed [t][d] (immediate form, P0 only)
#define XLOAD(BUF, toff) do {                                                  \
    int _dr = tid >> 3;                                                        \
    int _t4 = (tid & 7) << 2;                                                  \
    const float* _xb = x + ((size_t)b << 20) + t0 + (toff) + _t4;              \
    _Pragma("unroll")                                                          \
    for (int _pass = 0; _pass < 8; ++_pass) {                                  \
        int _d = (_pass << 5) + _dr;                                           \
        float4 _v = *(const float4*)(_xb + ((size_t)_d << 12));                \
        BUF[(_t4 + 0) * XLS + _d] = _v.x;                                      \
        BUF[(_t4 + 1) * XLS + _d] = _v.y;                                      \
        BUF[(_t4 + 2) * XLS + _d] = _v.z;                                      \
        BUF[(_t4 + 3) * XLS + _d] = _v.w;                                      \
    }                                                                          \
} while (0)

// split form: issue the 8 float4 loads into named regs xp0..xp7 ...
#define XP1(P, toff)                                                           \
    xp##P = *(const float4*)(x + ((size_t)b << 20) + t0 + (toff) + ((tid & 7) << 2) \
                             + ((size_t)((P << 5) + (tid >> 3)) << 12));
#define XPREF(toff) do {                                                       \
    XP1(0, toff) XP1(1, toff) XP1(2, toff) XP1(3, toff)                        \
    XP1(4, toff) XP1(5, toff) XP1(6, toff) XP1(7, toff)                        \
} while (0)
// ... and write them (transposed) into BUF later.
#define XW1(P, BUF) {                                                          \
    int _d = (P << 5) + (tid >> 3);                                            \
    int _t4 = (tid & 7) << 2;                                                  \
    BUF[(_t4 + 0) * XLS + _d] = xp##P.x;                                       \
    BUF[(_t4 + 1) * XLS + _d] = xp##P.y;                                       \
    BUF[(_t4 + 2) * XLS + _d] = xp##P.z;                                       \
    BUF[(_t4 + 3) * XLS + _d] = xp##P.w;                                       \
}
#define XWRITE(BUF) do {                                                       \
    XW1(0, BUF) XW1(1, BUF) XW1(2, BUF) XW1(3, BUF)                            \
    XW1(4, BUF) XW1(5, BUF) XW1(6, BUF) XW1(7, BUF)                            \
} while (0)

// load chunk `chn`'s 8 k-slices into named half8 regs PFX0..PFX7
#define LOADB(PFX, chn) do {                                                   \
    const uint4* _p = wsrc + ((chn) << 9) + lane;                              \
    PFX##0 = *(const half8*)(_p);                                              \
    PFX##1 = *(const half8*)(_p + 64);                                         \
    PFX##2 = *(const half8*)(_p + 128);                                        \
    PFX##3 = *(const half8*)(_p + 192);                                        \
    PFX##4 = *(const half8*)(_p + 256);                                        \
    PFX##5 = *(const half8*)(_p + 320);                                        \
    PFX##6 = *(const half8*)(_p + 384);                                        \
    PFX##7 = *(const half8*)(_p + 448);                                        \
} while (0)

#define MFMA16(A, B, C) __builtin_amdgcn_mfma_f32_16x16x32_f16((A), (B), (C), 0, 0, 0)

// compute chunk `ch` against named regs PFX0..PFX7, update b1/b2
#define COMPUTE(ch, PFX) do {                                                  \
    f32x4 a0 = {0.f, 0.f, 0.f, 0.f};                                           \
    f32x4 a1 = {0.f, 0.f, 0.f, 0.f};                                           \
    a0 = MFMA16(afrag[0][0], PFX##0, a0); a1 = MFMA16(afrag[1][0], PFX##0, a1);\
    a0 = MFMA16(afrag[0][1], PFX##1, a0); a1 = MFMA16(afrag[1][1], PFX##1, a1);\
    a0 = MFMA16(afrag[0][2], PFX##2, a0); a1 = MFMA16(afrag[1][2], PFX##2, a1);\
    a0 = MFMA16(afrag[0][3], PFX##3, a0); a1 = MFMA16(afrag[1][3], PFX##3, a1);\
    a0 = MFMA16(afrag[0][4], PFX##4, a0); a1 = MFMA16(afrag[1][4], PFX##4, a1);\
    a0 = MFMA16(afrag[0][5], PFX##5, a0); a1 = MFMA16(afrag[1][5], PFX##5, a1);\
    a0 = MFMA16(afrag[0][6], PFX##6, a0); a1 = MFMA16(afrag[1][6], PFX##6, a1);\
    a0 = MFMA16(afrag[0][7], PFX##7, a0); a1 = MFMA16(afrag[1][7], PFX##7, a1);\
    unsigned kg = (unsigned)(((ch) << 4) + n);                                 \
    float csub = wsql[kg];                                                     \
    _Pragma("unroll")                                                          \
    for (int i = 0; i < 4; ++i) {                                              \
        float v; unsigned p, o;                                                \
        v = fmaxf(a0[i] - csub, 0.0f);                                         \
        p = (__float_as_uint(v) & 0xFFFFFC00u) | kg;                           \
        o = b1[i];                                                             \
        b2[i] = umaxu(b2[i], uminu(p, o));                                     \
        b1[i] = umaxu(o, p);                                                   \
        v = fmaxf(a1[i] - csub, 0.0f);                                         \
        p = (__float_as_uint(v) & 0xFFFFFC00u) | kg;                           \
        o = b1[4 + i];                                                         \
        b2[4 + i] = umaxu(b2[4 + i], uminu(p, o));                             \
        b1[4 + i] = umaxu(o, p);                                               \
    }                                                                          \
} while (0)

// P2 quarter body. CUR holds x(QT); if DOPREF, x(QT+1) is loaded into xp regs at
// the top (latency hides under refine/gather/emit) and written to NXT at the end.
#define P2BODY(QT, CUR, NXT, DOPREF) do {                                      \
    if (DOPREF) XPREF(((QT) + 1) << 5);                                        \
    _Pragma("unroll")                                                          \
    for (int rr = 0; rr < 8; ++rr) {                                           \
        int r = (wv << 3) + rr;                                                \
        unsigned ci = ((const unsigned*)cndl)[((((QT) << 5) + r) << 2) + c] & 1023u; \
        const float* wr = w + (ci << 8);                                       \
        double s = 0.0;                                                        \
        _Pragma("unroll")                                                      \
        for (int dd = 0; dd < 4; ++dd) {                                       \
            int d4 = (dd << 6) + (dl << 2);                                    \
            float4 xv = *(const float4*)(&CUR[r * XLS + d4]);                  \
            float4 wv4 = *(const float4*)(wr + d4);                            \
            double e;                                                          \
            e = (double)xv.x - (double)wv4.x; s = fma(e, e, s);                \
            e = (double)xv.y - (double)wv4.y; s = fma(e, e, s);                \
            e = (double)xv.z - (double)wv4.z; s = fma(e, e, s);                \
            e = (double)xv.w - (double)wv4.w; s = fma(e, e, s);                \
        }                                                                      \
        _Pragma("unroll")                                                      \
        for (int m = 1; m <= 8; m <<= 1) s += __shfl_xor(s, m);                \
        if (dl == 0) disl[r][cidx] = s;                                        \
    }                                                                          \
    barrier_lgkm();                                                            \
    {                                                                          \
        double dm = 0.0;                                                       \
        if (tid < 32) {                                                        \
            uint4 cc = cndl[((QT) << 5) + tid];                                \
            unsigned i0 = cc.x & 1023u, i1 = cc.y & 1023u,                     \
                     i2 = cc.z & 1023u, i3 = cc.w & 1023u;                     \
            double dmv = disl[tid][0]; unsigned ci = i0;                       \
            double dk;                                                         \
            dk = disl[tid][1]; if (dk < dmv || (dk == dmv && i1 < ci)) { dmv = dk; ci = i1; } \
            dk = disl[tid][2]; if (dk < dmv || (dk == dmv && i2 < ci)) { dmv = dk; ci = i2; } \
            dk = disl[tid][3]; if (dk < dmv || (dk == dmv && i3 < ci)) { dmv = dk; ci = i3; } \
            winner[tid] = (int)ci;                                             \
            dm = dmv;                                                          \
            atomicAdd(&counts[ci], 1u);                                        \
        }                                                                      \
        if (wv == 0) {                                                         \
            dm += __shfl_xor(dm, 16); dm += __shfl_xor(dm, 8);                 \
            dm += __shfl_xor(dm, 4);  dm += __shfl_xor(dm, 2);                 \
            dm += __shfl_xor(dm, 1);  dm += __shfl_xor(dm, 32);                \
            if (lane == 0) atomicAdd(lsum, dm);                                \
        }                                                                      \
    }                                                                          \
    barrier_lgkm();                                                            \
    {                                                                          \
        int rowr = (wv << 3) + rr2;                                            \
        int win = winner[rowr];                                                \
        const float* wrow = w + (win << 8);                                    \
        _Pragma("unroll")                                                      \
        for (int cc2 = 0; cc2 < 4; ++cc2) {                                    \
            int col = (cc2 << 6) + (c8 << 3);                                  \
            float4 g0 = *(const float4*)(wrow + col);                          \
            float4 g1 = *(const float4*)(wrow + col + 4);                      \
            *(float4*)(&CUR[rowr * XLS + col]) = g0;                           \
            *(float4*)(&CUR[rowr * XLS + col + 4]) = g1;                       \
        }                                                                      \
    }                                                                          \
    barrier_lgkm();                                                            \
    {                                                                          \
        int dr = tid >> 3;                                                     \
        int t4 = (tid & 7) << 2;                                               \
        float* ob = out + ((size_t)b << 20) + t0 + ((QT) << 5) + t4;           \
        _Pragma("unroll")                                                      \
        for (int pass = 0; pass < 8; ++pass) {                                 \
            int d = (pass << 5) + dr;                                          \
            float4 o;                                                          \
            o.x = CUR[(t4 + 0) * XLS + d];                                     \
            o.y = CUR[(t4 + 1) * XLS + d];                                     \
            o.z = CUR[(t4 + 2) * XLS + d];                                     \
            o.w = CUR[(t4 + 3) * XLS + d];                                     \
            *(float4*)(ob + ((size_t)d << 12)) = o;                            \
        }                                                                      \
    }                                                                          \
    if (DOPREF) XWRITE(NXT);                                                   \
    barrier_lgkm();                                                            \
} while (0)

__global__ __launch_bounds__(256, 2) void fused(const float* __restrict__ x,
                                                const float* __restrict__ w,
                                                const _Float16* __restrict__ w16,
                                                const float* __restrict__ wsq,
                                                float* __restrict__ out,
                                                unsigned* __restrict__ counts,
                                                double* __restrict__ lsum) {
    __shared__ __align__(16) float xta[32 * XLS];  // 32.9 KB
    __shared__ __align__(16) float xtb[32 * XLS];  // 32.9 KB
    __shared__ __align__(16) float wsql[KK];       // 4 KB
    __shared__ __align__(16) uint4 cndl[128];      // 2 KB
    __shared__ double disl[32][4];
    __shared__ int winner[32];

    int tid = threadIdx.x, bid = blockIdx.x;
    int b = bid >> 5;
    int t0 = (bid & 31) << 7;                      // 128 rows per block
    int lane = tid & 63, wv = tid >> 6;
    int n = lane & 15, q = lane >> 4;

    ((float4*)wsql)[tid] = ((const float4*)wsq)[tid];

    // ---- P0: 4 quarter-loads (xta); wave p extracts its afrag from quarter p ----
    half8 afrag[2][8];
#pragma unroll
    for (int p = 0; p < 4; ++p) {
        XLOAD(xta, p << 5);
        __syncthreads();
        if (wv == p) {
#pragma unroll
            for (int mt = 0; mt < 2; ++mt) {
                int rl = (mt << 4) + n;
#pragma unroll
                for (int ks = 0; ks < 8; ++ks) {
                    const float* sp = &xta[rl * XLS + (ks << 5) + (q << 3)];
                    half8 f;
#pragma unroll
                    for (int j = 0; j < 8; ++j) f[j] = (_Float16)sp[j];
                    afrag[mt][ks] = f;
                }
            }
        }
        __syncthreads();
    }

    // prefetch quarter-0 x into regs: lands during P1, written to xta post-merge
    float4 xp0, xp1, xp2, xp3, xp4, xp5, xp6, xp7;
    XPREF(0);

    // ---- P1: rank (barrier-free reg-stream) ----
    unsigned b1[8], b2[8];
#pragma unroll
    for (int i = 0; i < 8; ++i) { b1[i] = 0u; b2[i] = 0u; }

    const uint4* wsrc = (const uint4*)w16;
    half8 bA0, bA1, bA2, bA3, bA4, bA5, bA6, bA7;
    half8 bB0, bB1, bB2, bB3, bB4, bB5, bB6, bB7;

    LOADB(bA, 0);
    for (int ch = 0; ch < 64; ch += 2) {
        LOADB(bB, ch + 1);
        COMPUTE(ch, bA);
        if (ch + 2 < 64) LOADB(bA, ch + 2);
        COMPUTE(ch + 1, bB);
    }

    // merge the 16 column-lanes' top-2 -> per-row top-4 -> cndl (LDS)
#pragma unroll
    for (int s = 0; s < 8; ++s) {
        unsigned v0 = b1[s], v1 = b2[s], v2 = 0u, v3 = 0u;
#pragma unroll
        for (int m = 1; m <= 8; m <<= 1) {
            unsigned e0 = __shfl_xor(v0, m);
            unsigned e1 = __shfl_xor(v1, m);
            unsigned e2 = __shfl_xor(v2, m);
            unsigned e3 = __shfl_xor(v3, m);
#pragma unroll
            for (int u = 0; u < 4; ++u) {
                unsigned e = (u == 0) ? e0 : (u == 1) ? e1 : (u == 2) ? e2 : e3;
                unsigned t;
                t = umaxu(e, v0); e = uminu(e, v0); v0 = t;
                t = umaxu(e, v1); e = uminu(e, v1); v1 = t;
                t = umaxu(e, v2); e = uminu(e, v2); v2 = t;
                v3 = umaxu(e, v3);
            }
        }
        if (n == 0) {
            int row_local = (wv << 5) + ((s >> 2) << 4) + (q << 2) + (s & 3);
            cndl[row_local] = make_uint4(v0, v1, v2, v3);
        }
    }
    XWRITE(xta);          // quarter-0 x into xta (P0's use of xta is long done)
    __syncthreads();      // full barrier: cndl + xta visible to all

    // ---- P2: 4 quarters, double-buffered ----
    int c = lane >> 4, dl = lane & 15;
    int cidx = c;                                  // disl column index
    int rr2 = lane >> 3, c8 = lane & 7;            // conflict-free gather mapping
    P2BODY(0, xta, xtb, 1);
    P2BODY(1, xtb, xta, 1);
    P2BODY(2, xta, xtb, 1);
    P2BODY(3, xtb, xta, 0);
}

// ---------------- finalize ----------------
__global__ void finalize(const unsigned* __restrict__ counts,
                         const double* __restrict__ lsum,
                         float* __restrict__ out2) {
    __shared__ double part[256];
    int tid = threadIdx.x;
    double s = 0.0;
    for (int i = tid; i < KK; i += 256) {
        double p = (double)counts[i] / (double)NROW;
        s += p * log(p + 1e-10);
    }
    part[tid] = s;
    __syncthreads();
    for (int st = 128; st > 0; st >>= 1) {
        if (tid < st) part[tid] += part[tid + st];
        __syncthreads();
    }
    if (tid == 0) {
        out2[0] = (float)(1.25 * (*lsum) / ((double)NROW * (double)DD));
        out2[1] = (float)exp(-part[0]);
    }
}

extern "C" void kernel_launch(void* const* d_in, const int* in_sizes, int n_in,
                              void* d_out, int out_size, void* d_ws, size_t ws_size,
                              hipStream_t stream) {
    const float* x = (const float*)d_in[0];
    const float* w = (const float*)d_in[1];
    float* out = (float*)d_out;
    char* ws = (char*)d_ws;
    _Float16* w16    = (_Float16*)ws;                         // 524288 B
    unsigned* counts = (unsigned*)(ws + 524288);              // 4 KB
    float*    wsq    = (float*)(ws + 528384);                 // 4 KB
    double*   lsum   = (double*)(ws + 532480);                // 8 B

    prep<<<128, 256, 0, stream>>>(w, w16, counts, lsum, wsq);
    fused<<<512, 256, 0, stream>>>(x, w, w16, wsq, out, counts, lsum);
    finalize<<<1, 256, 0, stream>>>(counts, lsum, out + (size_t)NROW * DD);
}